// Round 8
// baseline (673.198 us; speedup 1.0000x reference)
//
#include <hip/hip_runtime.h>
#include <math.h>

#define TPB 256
#define PMS 3200       // pm stride >= gH (3157)

typedef _Float16 h8 __attribute__((ext_vector_type(8)));
typedef _Float16 hf;

// Node records: 32 B (16 f16) -> table 3.23 MB, L2-resident (R1: 64B records spill L2).
// Agg kernels at per-edge L1-miss floor (R2/R3).
// R7 lesson: staged scatter chain (hist2+sbase+scat+bbuild) = ~77us with scat_k
// serialized at 12% occupancy. This round: DIRECT CSR build — per-node degree
// (global atomics, 404KB L2-resident), 2-level scan -> rp/dinv/cursor, then
// direct scatter csr[atomicAdd(&cursor[c],1)]=r (scattered writes absorbed by
// 256MB L3). No pairs, no pads, 2 fewer heavy kernels. Within-node edge order
// nondeterministic (fp-association only; tolerated since R4).

// ===================== threefry2x32-20 (JAX-exact, PARTITIONABLE mode) + gumbel =====================
__device__ __forceinline__ float jax_gumbel(unsigned key, unsigned i) {
  unsigned x0 = 0u, x1 = i;
  unsigned ks0 = 0u, ks1 = key, ks2 = key ^ 0x1BD11BDAu;
  x0 += ks0; x1 += ks1;
#define TFR(r) { x0 += x1; x1 = (x1 << (r)) | (x1 >> (32 - (r))); x1 ^= x0; }
  TFR(13) TFR(15) TFR(26) TFR(6)
  x0 += ks1; x1 += ks2 + 1u;
  TFR(17) TFR(29) TFR(16) TFR(24)
  x0 += ks2; x1 += ks0 + 2u;
  TFR(13) TFR(15) TFR(26) TFR(6)
  x0 += ks0; x1 += ks1 + 3u;
  TFR(17) TFR(29) TFR(16) TFR(24)
  x0 += ks1; x1 += ks2 + 4u;
  TFR(13) TFR(15) TFR(26) TFR(6)
  x0 += ks2; x1 += ks0 + 5u;
#undef TFR
  unsigned bits = x0 ^ x1;
  float f = __uint_as_float((bits >> 9) | 0x3f800000u) - 1.0f;
  float u = (f == 0.0f) ? 1.17549435e-38f : f;
  return -logf(-logf(u));
}

// ===================== zero deg =====================
__global__ void zero_k(int* __restrict__ deg, int n4) {
  int i = blockIdx.x * TPB + threadIdx.x;
  if (i < n4) ((int4*)deg)[i] = make_int4(0, 0, 0, 0);
}

// ===================== prep: W23 = W2@W3 (16x32), bvA = b1@W23, bvB = b2@W3 =====================
__global__ void prep_k(const float* __restrict__ W2, const float* __restrict__ W3,
                       const float* __restrict__ b1, const float* __restrict__ b2,
                       float* __restrict__ W23, float* __restrict__ bvA, float* __restrict__ bvB) {
  int t = threadIdx.x;
  for (int idx = t; idx < 512; idx += TPB) {
    int i = idx >> 5, j = idx & 31;
    float s = 0.f;
    for (int k = 0; k < 24; k++) s += W2[i * 24 + k] * W3[k * 32 + j];
    W23[idx] = s;
  }
  __syncthreads();
  if (t < 32) {
    float sA = 0.f;
    for (int i = 0; i < 16; i++) sA += b1[i] * W23[i * 32 + t];
    bvA[t] = sA;
    float sB = 0.f;
    for (int k = 0; k < 24; k++) sB += b2[k] * W3[k * 32 + t];
    bvB[t] = sB;
  }
}

// ===================== degree count + fused edge->float copy =====================
__global__ void deg_k(const int* __restrict__ row, const int* __restrict__ col,
                      int* __restrict__ deg, float* __restrict__ e0, float* __restrict__ e1,
                      int ne) {
  int stride = gridDim.x * TPB;
  for (int i = blockIdx.x * TPB + threadIdx.x; i < ne; i += stride) {
    int c = col[i];
    int r = row[i];
    atomicAdd(&deg[c], 1);
    e0[i] = (float)r;
    e1[i] = (float)c;
  }
}

// ===================== 2-level scan over deg -> rp, cursor, dinv =====================
__global__ void scan1_k(const int* __restrict__ a, int* __restrict__ bsums, int n) {
  int t = threadIdx.x;
  int base = blockIdx.x * 1024 + t * 4;
  int s = 0;
#pragma unroll
  for (int k = 0; k < 4; k++) { int i = base + k; if (i < n) s += a[i]; }
  __shared__ int red[TPB];
  red[t] = s; __syncthreads();
  for (int st = 128; st > 0; st >>= 1) { if (t < st) red[t] += red[t + st]; __syncthreads(); }
  if (t == 0) bsums[blockIdx.x] = red[0];
}

__global__ void scan_single_k(int* a, int m) {
  __shared__ int sc[TPB];
  int t = threadIdx.x;
  int v[4]; int s = 0;
#pragma unroll
  for (int k = 0; k < 4; k++) { int i = t * 4 + k; v[k] = (i < m) ? a[i] : 0; s += v[k]; }
  sc[t] = s; __syncthreads();
  for (int off = 1; off < TPB; off <<= 1) {
    int add = (t >= off) ? sc[t - off] : 0;
    __syncthreads();
    sc[t] += add;
    __syncthreads();
  }
  int excl = sc[t] - s;
#pragma unroll
  for (int k = 0; k < 4; k++) { int i = t * 4 + k; if (i < m) a[i] = excl; excl += v[k]; }
  if (t == TPB - 1) a[m] = excl;
}

__global__ void scan3x_k(const int* __restrict__ deg, const int* __restrict__ bsums,
                         int* __restrict__ rp, int* __restrict__ cursor,
                         float* __restrict__ dinv, int n, int ne) {
  int t = threadIdx.x;
  int base = blockIdx.x * 1024 + t * 4;
  int v[4]; int tsum = 0;
#pragma unroll
  for (int k = 0; k < 4; k++) {
    int vv = (base + k < n) ? deg[base + k] : 0;
    v[k] = vv; tsum += vv;
  }
  __shared__ int sc[TPB];
  sc[t] = tsum; __syncthreads();
  for (int off = 1; off < TPB; off <<= 1) {
    int add = (t >= off) ? sc[t - off] : 0;
    __syncthreads();
    sc[t] += add;
    __syncthreads();
  }
  int excl = sc[t] - tsum + bsums[blockIdx.x];
#pragma unroll
  for (int k = 0; k < 4; k++) {
    int i = base + k;
    if (i < n) {
      rp[i] = excl;
      cursor[i] = excl;
      dinv[i] = 1.0f / sqrtf((float)(v[k] + 1));
    }
    excl += v[k];
  }
  if (blockIdx.x == 0 && t == 0) rp[n] = ne;
}

// ===================== direct scatter: csr[atomicAdd(cursor[c])] = r =====================
__global__ void scat2_k(const int* __restrict__ row, const int* __restrict__ col,
                        int* __restrict__ cursor, int* __restrict__ csr, int ne) {
  int stride = gridDim.x * TPB;
  for (int i = blockIdx.x * TPB + threadIdx.x; i < ne; i += stride) {
    int c = col[i];
    int r = row[i];
    int q = atomicAdd(&cursor[c], 1);
    csr[q] = r;
  }
}

// ===================== s0 = dinv * (x W1), fp16 output (16-wide) =====================
__global__ void gemm16h_k(const float* __restrict__ A, const float* __restrict__ A2, int nsplit,
                          const float* __restrict__ W, const float* __restrict__ dinv,
                          hf* __restrict__ out, int n) {
  constexpr int FIN = 32, FOUT = 16, FP = 16;
  constexpr int NODES = TPB / FP;
  __shared__ float Ws[FIN * FOUT];
  __shared__ float Hs[NODES * (FIN + 1)];
  int t = threadIdx.x;
  int base = blockIdx.x * NODES;
  for (int i = t; i < FIN * FOUT; i += TPB) Ws[i] = W[i];
  for (int i = t; i < NODES * FIN; i += TPB) {
    int nl = i / FIN, k = i - nl * FIN;
    int g = base + nl;
    float v = 0.f;
    if (g < n) v = (g < nsplit) ? A[(size_t)g * FIN + k] : A2[(size_t)(g - nsplit) * FIN + k];
    Hs[nl * (FIN + 1) + k] = v;
  }
  __syncthreads();
  int nl = t / FP, j = t % FP;
  int g = base + nl;
  if (g < n) {
    float acc = 0.f;
#pragma unroll
    for (int k = 0; k < FIN; k++) acc += Hs[nl * (FIN + 1) + k] * Ws[k * FOUT + j];
    out[(size_t)g * FOUT + j] = (hf)(acc * dinv[g]);
  }
}

// ===================== fp16 hop + fused scalar chain: 8 nodes/wave, aligned int4 csr ==========
__global__ void agghs_k(const h8* __restrict__ ts, const int* __restrict__ csr,
                        const int* __restrict__ rp, const float* __restrict__ dinv,
                        const float* __restrict__ sin_, float* __restrict__ u_out,
                        float* __restrict__ us_out, h8* __restrict__ outv, int n) {
  int wave = blockIdx.x * (TPB / 64) + (threadIdx.x >> 6);
  int lane = threadIdx.x & 63;
  int j = lane & 1;
  int grp = (lane >> 1) & 3;
  int nl = lane >> 3;
  int c = wave * 8 + nl;
  bool valid = (c < n);
  float acc[8] = {0.f, 0.f, 0.f, 0.f, 0.f, 0.f, 0.f, 0.f};
  float accS = 0.f;
  if (valid) {
    int s = rp[c], e = rp[c + 1];
    int ch0 = s >> 2, ch1 = (e + 3) >> 2;
    int nch = ch1 - ch0;
    int k0 = ch0 + ((nch * grp) >> 2);
    int k1 = ch0 + ((nch * (grp + 1)) >> 2);
    for (int ch = k0; ch < k1; ch++) {
      int base = ch << 2;
      int4 e4 = *(const int4*)(csr + base);   // 16B aligned always
      bool b0 = (base     >= s) & (base     < e);
      bool b1 = (base + 1 >= s) & (base + 1 < e);
      bool b2 = (base + 2 >= s) & (base + 2 < e);
      bool b3 = (base + 3 >= s) & (base + 3 < e);
      int r0 = b0 ? e4.x : 0;
      int r1 = b1 ? e4.y : 0;
      int r2 = b2 ? e4.z : 0;
      int r3 = b3 ? e4.w : 0;
      float m0 = b0 ? 1.f : 0.f, m1 = b1 ? 1.f : 0.f;
      float m2 = b2 ? 1.f : 0.f, m3 = b3 ? 1.f : 0.f;
      h8 v0 = ts[(r0 << 1) | j];
      h8 v1 = ts[(r1 << 1) | j];
      h8 v2 = ts[(r2 << 1) | j];
      h8 v3 = ts[(r3 << 1) | j];
      float sA = sin_[j ? r2 : r0];
      float sB = sin_[j ? r3 : r1];
      accS += sA * (j ? m2 : m0) + sB * (j ? m3 : m1);
#pragma unroll
      for (int k = 0; k < 8; k++)
        acc[k] += m0 * (float)v0[k] + m1 * (float)v1[k] + m2 * (float)v2[k] + m3 * (float)v3[k];
    }
  }
  accS += __shfl_xor(accS, 1, 64);
#pragma unroll
  for (int off = 2; off <= 4; off <<= 1) {
#pragma unroll
    for (int k = 0; k < 8; k++) acc[k] += __shfl_xor(acc[k], off, 64);
    accS += __shfl_xor(accS, off, 64);
  }
  if (valid && grp == 0) {
    h8 self = ts[(c << 1) | j];
    float d = dinv[c];
    float scl = d * d;
    h8 o;
#pragma unroll
    for (int k = 0; k < 8; k++) o[k] = (hf)(scl * (acc[k] + (float)self[k]));
    outv[(c << 1) | j] = o;
    if (j == 0) {
      float u = d * (accS + sin_[c]);
      u_out[c] = u;
      if (us_out) us_out[c] = u * d;
    }
  }
}

// ===================== final hop + combine + FUSED HEADS (32 nodes/block) =====================
__global__ void agghch_k(const h8* __restrict__ ts, const int* __restrict__ csr,
                         const int* __restrict__ rp, const float* __restrict__ dinv,
                         const float* __restrict__ a1, const float* __restrict__ a2,
                         const float* __restrict__ W23, const float* __restrict__ bvA,
                         const float* __restrict__ bvB, const float* __restrict__ b3,
                         const float* __restrict__ Ws1, const float* __restrict__ bs1,
                         const float* __restrict__ ws2, const float* __restrict__ bs2,
                         const float* __restrict__ We1, const float* __restrict__ be1,
                         const float* __restrict__ we2, const float* __restrict__ be2,
                         float* __restrict__ out, float* __restrict__ slog,
                         float* __restrict__ elog, float* __restrict__ pm, int n) {
  __shared__ float Ws[512], vA[32], vB[32], vb[32];
  __shared__ float t3s[32][17];
  __shared__ float h3s[32][33];
  __shared__ float W1s[512], W2s[768], b1s[16], b2s[24], v1s[16], v2s[24], sb2[2];
  __shared__ float sm1[32], su1[32], sm2[32], su2[32];
  int t = threadIdx.x;
  for (int i = t; i < 512; i += TPB) { Ws[i] = W23[i]; W1s[i] = Ws1[i]; }
  for (int i = t; i < 768; i += TPB) W2s[i] = We1[i];
  if (t < 32) { vA[t] = bvA[t]; vB[t] = bvB[t]; vb[t] = b3[t]; }
  if (t < 16) { b1s[t] = bs1[t]; v1s[t] = ws2[t]; }
  if (t < 24) { b2s[t] = be1[t]; v2s[t] = we2[t]; }
  if (t == 0) { sb2[0] = bs2[0]; sb2[1] = be2[0]; }
  int wave = t >> 6;
  int lane = t & 63;
  int j = lane & 1;
  int grp = (lane >> 1) & 3;
  int nl = lane >> 3;
  int nlb = wave * 8 + nl;              // node-in-block 0..31
  int c = blockIdx.x * 32 + nlb;
  bool valid = (c < n);
  float acc[8] = {0.f, 0.f, 0.f, 0.f, 0.f, 0.f, 0.f, 0.f};
  if (valid) {
    int s = rp[c], e = rp[c + 1];
    int ch0 = s >> 2, ch1 = (e + 3) >> 2;
    int nch = ch1 - ch0;
    int k0 = ch0 + ((nch * grp) >> 2);
    int k1 = ch0 + ((nch * (grp + 1)) >> 2);
    for (int ch = k0; ch < k1; ch++) {
      int base = ch << 2;
      int4 e4 = *(const int4*)(csr + base);
      bool b0 = (base     >= s) & (base     < e);
      bool b1 = (base + 1 >= s) & (base + 1 < e);
      bool b2 = (base + 2 >= s) & (base + 2 < e);
      bool b3b = (base + 3 >= s) & (base + 3 < e);
      int r0 = b0 ? e4.x : 0;
      int r1 = b1 ? e4.y : 0;
      int r2 = b2 ? e4.z : 0;
      int r3 = b3b ? e4.w : 0;
      float m0 = b0 ? 1.f : 0.f, m1 = b1 ? 1.f : 0.f;
      float m2 = b2 ? 1.f : 0.f, m3 = b3b ? 1.f : 0.f;
      h8 v0 = ts[(r0 << 1) | j];
      h8 v1 = ts[(r1 << 1) | j];
      h8 v2 = ts[(r2 << 1) | j];
      h8 v3 = ts[(r3 << 1) | j];
#pragma unroll
      for (int k = 0; k < 8; k++)
        acc[k] += m0 * (float)v0[k] + m1 * (float)v1[k] + m2 * (float)v2[k] + m3 * (float)v3[k];
    }
  }
#pragma unroll
  for (int off = 2; off <= 4; off <<= 1) {
#pragma unroll
    for (int k = 0; k < 8; k++) acc[k] += __shfl_xor(acc[k], off, 64);
  }
  if (valid && grp == 0) {
    h8 self = ts[(c << 1) | j];
    float d = dinv[c];
#pragma unroll
    for (int k = 0; k < 8; k++) t3s[nlb][j * 8 + k] = d * (acc[k] + (float)self[k]);
  }
  __syncthreads();
  // combine -> h3 (to global + LDS)
  int n2 = t >> 3, jb = t & 7;          // 32 nodes x 8 base channels
  int g = blockIdx.x * 32 + n2;
  if (g < n) {
    float av = a1[g], bv = a2[g];
#pragma unroll
    for (int q = 0; q < 4; q++) {
      int j2 = jb + q * 8;
      float acc2 = 0.f;
#pragma unroll
      for (int k = 0; k < 16; k++) acc2 += t3s[n2][k] * Ws[k * 32 + j2];
      float hv = acc2 + bv * vA[j2] + av * vB[j2] + vb[j2];
      out[(size_t)g * 32 + j2] = hv;
      h3s[n2][j2] = hv;
    }
  }
  __syncthreads();
  // heads: 8 threads per node, hidden units strided by 8
  float sP = 0.f, eP = 0.f;
  if (g < n) {
#pragma unroll
    for (int jj = 0; jj < 16; jj += 8) {
      int jh = jj + jb;
      float a = b1s[jh];
#pragma unroll
      for (int k = 0; k < 32; k++) a += h3s[n2][k] * W1s[k * 16 + jh];
      a = fminf(fmaxf(a, 0.f), 6.f);
      sP += a * v1s[jh];
    }
#pragma unroll
    for (int jj = 0; jj < 24; jj += 8) {
      int jh = jj + jb;
      float a = b2s[jh];
#pragma unroll
      for (int k = 0; k < 32; k++) a += h3s[n2][k] * W2s[k * 24 + jh];
      a = fminf(fmaxf(a, 0.f), 6.f);
      eP += a * v2s[jh];
    }
  }
#pragma unroll
  for (int off = 1; off <= 4; off <<= 1) {
    sP += __shfl_xor(sP, off, 64);
    eP += __shfl_xor(eP, off, 64);
  }
  if (jb == 0) {
    float s = -3.402823466e+38f, e2 = -3.402823466e+38f, w = 0.f;
    if (g < n) {
      s = sP + sb2[0]; e2 = eP + sb2[1]; w = 1.f;
      slog[g] = s; elog[g] = e2;
    }
    sm1[n2] = s;  su1[n2] = w;
    sm2[n2] = e2; su2[n2] = w;
  }
  __syncthreads();
  // block online-softmax partials over 32 nodes
  for (int st = 16; st > 0; st >>= 1) {
    if (t < st) {
      float M = fmaxf(sm1[t], sm1[t + st]);
      su1[t] = su1[t] * expf(sm1[t] - M) + su1[t + st] * expf(sm1[t + st] - M);
      sm1[t] = M;
      float M2 = fmaxf(sm2[t], sm2[t + st]);
      su2[t] = su2[t] * expf(sm2[t] - M2) + su2[t + st] * expf(sm2[t + st] - M2);
      sm2[t] = M2;
    }
    __syncthreads();
  }
  if (t == 0) {
    pm[blockIdx.x] = sm1[0]; pm[PMS + blockIdx.x] = su1[0];
    pm[2 * PMS + blockIdx.x] = sm2[0]; pm[3 * PMS + blockIdx.x] = su2[0];
  }
}

// ===================== fused probs write + gumbel argmax (finalizers folded in) ==========
template <int HEAD>
__global__ void pargmax_k(const float* __restrict__ logit, const float* __restrict__ pm, int nb,
                          const float* __restrict__ sval, const int* __restrict__ sidx,
                          float* __restrict__ outp, unsigned key, int n, int ngraph,
                          float* __restrict__ pval, int* __restrict__ pidx,
                          float* __restrict__ dnode) {
  int t = threadIdx.x;
  __shared__ float smM[TPB], smS[TPB];
  __shared__ float sv0[TPB]; __shared__ int si0[TPB];
  // inline softmax finalize over block partials
  const float* pmM = pm + (HEAD ? 2 * PMS : 0);
  const float* pmS = pm + (HEAD ? 3 * PMS : PMS);
  float m = -3.402823466e+38f, s0 = 0.f;
  for (int i = t; i < nb; i += TPB) {
    float bm = pmM[i], bs = pmS[i];
    float M = fmaxf(m, bm);
    s0 = s0 * expf(m - M) + bs * expf(bm - M); m = M;
  }
  smM[t] = m; smS[t] = s0; __syncthreads();
  for (int st = 128; st > 0; st >>= 1) {
    if (t < st) {
      float M = fmaxf(smM[t], smM[t + st]);
      smS[t] = smS[t] * expf(smM[t] - M) + smS[t + st] * expf(smM[t + st] - M);
      smM[t] = M;
    }
    __syncthreads();
  }
  float mx = smM[0], sm = smS[0];
  // inline start-argmax finalize (HEAD==1 only; sval/sidx have exactly 256 entries)
  int ban = -1;
  if (HEAD) {
    sv0[t] = sval[t]; si0[t] = sidx[t]; __syncthreads();
    for (int st = 128; st > 0; st >>= 1) {
      if (t < st) {
        float v2 = sv0[t + st]; int i2 = si0[t + st];
        if (v2 > sv0[t] || (v2 == sv0[t] && i2 < si0[t])) { sv0[t] = v2; si0[t] = i2; }
      }
      __syncthreads();
    }
    ban = si0[0];
    if (blockIdx.x == 0 && t == 0) dnode[0] = (float)ban;
  }
  float bv = -3.402823466e+38f;
  int bi = 0x7fffffff;
  for (int i = blockIdx.x * TPB + t; i < n; i += gridDim.x * TPB) {
    float p = expf(logit[i] - mx) / sm;
    if (HEAD == 0) { if (i >= ngraph) p = 0.f; }
    else           { if (i == ban) p = 0.f; }
    if (p == 0.f) p = 1e-10f;
    outp[i] = p;
    float v = logf(p) + jax_gumbel(key, (unsigned)i);
    if (v > bv) { bv = v; bi = i; }
  }
  __shared__ float sv[TPB]; __shared__ int si[TPB];
  sv[t] = bv; si[t] = bi; __syncthreads();
  for (int st = 128; st > 0; st >>= 1) {
    if (t < st) {
      float v2 = sv[t + st]; int i2 = si[t + st];
      if (v2 > sv[t] || (v2 == sv[t] && i2 < si[t])) { sv[t] = v2; si[t] = i2; }
    }
    __syncthreads();
  }
  if (t == 0) { pval[blockIdx.x] = sv[0]; pidx[blockIdx.x] = si[0]; }
}

__global__ void argmax_fin_end_k(const float* pval, const int* pidx, int nb,
                                 const float* dstart, float* p_end, float* p_e0, float* p_e1) {
  int t = threadIdx.x;
  float bv = (t < nb) ? pval[t] : -3.402823466e+38f;
  int bi = (t < nb) ? pidx[t] : 0x7fffffff;
  __shared__ float sv[TPB]; __shared__ int si[TPB];
  sv[t] = bv; si[t] = bi; __syncthreads();
  for (int st = 128; st > 0; st >>= 1) {
    if (t < st) {
      float v2 = sv[t + st]; int i2 = si[t + st];
      if (v2 > sv[t] || (v2 == sv[t] && i2 < si[t])) { sv[t] = v2; si[t] = i2; }
    }
    __syncthreads();
  }
  if (t == 0) {
    int en = si[0];
    p_end[0] = (float)en;
    p_e0[0] = dstart[0];
    p_e1[0] = (float)en;
  }
}

// ===================== launch =====================
extern "C" void kernel_launch(void* const* d_in, const int* in_sizes, int n_in,
                              void* d_out, int out_size, void* d_ws, size_t ws_size,
                              hipStream_t stream) {
  const float* x    = (const float*)d_in[0];
  const float* cand = (const float*)d_in[1];
  const int*   ei   = (const int*)d_in[2];
  const float* W1 = (const float*)d_in[3];  const float* b1  = (const float*)d_in[4];
  const float* W2 = (const float*)d_in[5];  const float* b2  = (const float*)d_in[6];
  const float* W3 = (const float*)d_in[7];  const float* b3  = (const float*)d_in[8];
  const float* Ws1= (const float*)d_in[9];  const float* bs1 = (const float*)d_in[10];
  const float* Ws2= (const float*)d_in[11]; const float* bs2 = (const float*)d_in[12];
  const float* We1= (const float*)d_in[13]; const float* be1 = (const float*)d_in[14];
  const float* We2= (const float*)d_in[15]; const float* be2 = (const float*)d_in[16];

  const int nG = in_sizes[0] / 32, nC = in_sizes[1] / 32;
  const int n  = nG + nC;            // 101000
  const int ne = in_sizes[2] / 2;    // 3200000

  float* out = (float*)d_out;
  const size_t OFF1 = (size_t)n * 32;
  const size_t OFF2 = OFF1 + n;
  const size_t OFF3 = OFF2 + n;
  const size_t OFF4 = OFF3 + 1;
  const size_t OFF5 = OFF4 + 1;     // edge_index_new region: 2*(ne+1) floats

  // ---- workspace layout ----
  float* wf = (float*)d_ws;
  int*   wi = (int*)d_ws;
  size_t NP = (((size_t)n + 2) + 63) & ~(size_t)63;
  size_t o = 0;
  int*   rp    = wi + o; o += NP;
  int*   deg   = wi + o; o += NP;
  int*   bcur  = wi + o; o += NP;
  int*   bsums = wi + o; o += 384;
  float* dinv  = wf + o; o += NP;
  float* a1v   = wf + o; o += NP;
  float* a1s   = wf + o; o += NP;
  float* a2v   = wf + o; o += NP;
  float* w23   = wf + o; o += 512;
  float* bvA   = wf + o; o += 64;
  float* bvB   = wf + o; o += 64;
  float* slogv = wf + o; o += NP;
  float* elogv = wf + o; o += NP;
  float* pmA   = wf + o; o += 4 * PMS;
  float* aval  = wf + o; o += 512;
  int*   aidx  = wi + o; o += 512;
  hf*    hh0   = (hf*)(wf + o); o += (size_t)n * 8 + 64;    // n*16 halves (32B records)
  hf*    hh1   = (hf*)(wf + o); o += (size_t)n * 8 + 64;
  o = (o + 3) & ~(size_t)3;                                  // 16B-align csr for int4 reads
  int*   csr   = wi + o; o += (size_t)ne + 64;

  const int* row = ei;
  const int* col = ei + ne;

  const int nsc = (n + 1023) / 1024;                         // scan blocks (99)
  const int nz4 = (int)(NP >> 2);

  // ---- direct CSR build: zero -> deg(+edgecopy) -> scans -> scatter ----
  zero_k<<<(nz4 + TPB - 1) / TPB, TPB, 0, stream>>>(deg, nz4);
  prep_k<<<1, TPB, 0, stream>>>(W2, W3, b1, b2, w23, bvA, bvB);
  deg_k<<<2048, TPB, 0, stream>>>(row, col, deg, out + OFF5, out + OFF5 + ne + 1, ne);
  scan1_k<<<nsc, TPB, 0, stream>>>(deg, bsums, n);
  scan_single_k<<<1, TPB, 0, stream>>>(bsums, nsc);
  scan3x_k<<<nsc, TPB, 0, stream>>>(deg, bsums, rp, bcur, dinv, n, ne);
  scat2_k<<<2048, TPB, 0, stream>>>(row, col, bcur, csr, ne);

  // ---- fused-linear GCN: h3 = A^3 (x W1) W23 + a2*bvA + a1*bvB + b3 ----
  gemm16h_k<<<(n + 15) / 16, TPB, 0, stream>>>(x, cand, nG, W1, dinv, hh0, n);
  int gH = (n + 31) / 32;
  agghs_k<<<gH, TPB, 0, stream>>>((const h8*)hh0, csr, rp, dinv, dinv, a1v, a1s, (h8*)hh1, n);
  agghs_k<<<gH, TPB, 0, stream>>>((const h8*)hh1, csr, rp, dinv, a1s, a2v, nullptr, (h8*)hh0, n);
  agghch_k<<<gH, TPB, 0, stream>>>((const h8*)hh0, csr, rp, dinv, a1v, a2v,
                                   w23, bvA, bvB, b3,
                                   Ws1, bs1, Ws2, bs2, We1, be1, We2, be2,
                                   out, slogv, elogv, pmA, n);

  // start head: probs + categorical(42); softmax finalize inlined per block
  pargmax_k<0><<<256, TPB, 0, stream>>>(slogv, pmA, gH, nullptr, nullptr,
                                        out + OFF1, 42u, n, nG, aval, aidx, nullptr);

  // end head: probs (zero at start) + categorical(43); ban derived per block
  pargmax_k<1><<<256, TPB, 0, stream>>>(elogv, pmA, gH, aval, aidx,
                                        out + OFF2, 43u, n, nG, aval + 256, aidx + 256,
                                        out + OFF3);
  argmax_fin_end_k<<<1, TPB, 0, stream>>>(aval + 256, aidx + 256, 256, out + OFF3,
                                          out + OFF4, out + OFF5 + ne, out + OFF5 + 2 * (size_t)ne + 1);
}

// Round 9
// 338.832 us; speedup vs baseline: 1.9868x; 1.9868x over previous
//
#include <hip/hip_runtime.h>
#include <math.h>

#define TPB 256
#define STPB 512       // scat_k block size (R8: occupancy fix — 8 waves on the 47KiB LDS block)
#define BNODES 256     // nodes per bucket (col>>8)
#define EPB 8192       // edges per block in hist/scatter
#define SENT (-1)
#define MAXBKT 512     // padded bucket-array size (NBKT=395 for this problem)
#define STAGE_CAP 9472 // >= EPB + 3*NBKT(395) = 9377
#define PMS 3200       // pm stride >= gH (3157)

typedef _Float16 h8 __attribute__((ext_vector_type(8)));
typedef _Float16 hf;

// Node records: 32 B (16 f16) -> table 3.23 MB, L2-resident (R1: 64B spills L2).
// Agg kernels at per-edge L1-miss floor (R2/R3).
// R8 lesson (direct scatter): scattered global atomics/stores cost a FULL 64B line
// each at the memory controller (WRITE_SIZE 42->195MB, 290us) — LDS staging for
// coalesced output is mandatory. This round: R7 pipeline exactly, scat_k at 512
// threads (same LDS, 2x waves -> occupancy 12%->25%).

// ===================== threefry2x32-20 (JAX-exact, PARTITIONABLE mode) + gumbel =====================
__device__ __forceinline__ float jax_gumbel(unsigned key, unsigned i) {
  unsigned x0 = 0u, x1 = i;
  unsigned ks0 = 0u, ks1 = key, ks2 = key ^ 0x1BD11BDAu;
  x0 += ks0; x1 += ks1;
#define TFR(r) { x0 += x1; x1 = (x1 << (r)) | (x1 >> (32 - (r))); x1 ^= x0; }
  TFR(13) TFR(15) TFR(26) TFR(6)
  x0 += ks1; x1 += ks2 + 1u;
  TFR(17) TFR(29) TFR(16) TFR(24)
  x0 += ks2; x1 += ks0 + 2u;
  TFR(13) TFR(15) TFR(26) TFR(6)
  x0 += ks0; x1 += ks1 + 3u;
  TFR(17) TFR(29) TFR(16) TFR(24)
  x0 += ks1; x1 += ks2 + 4u;
  TFR(13) TFR(15) TFR(26) TFR(6)
  x0 += ks2; x1 += ks0 + 5u;
#undef TFR
  unsigned bits = x0 ^ x1;
  float f = __uint_as_float((bits >> 9) | 0x3f800000u) - 1.0f;
  float u = (f == 0.0f) ? 1.17549435e-38f : f;
  return -logf(-logf(u));
}

// ===================== prep: W23 = W2@W3, bvA, bvB + zero breal =====================
__global__ void prep_k(const float* __restrict__ W2, const float* __restrict__ W3,
                       const float* __restrict__ b1, const float* __restrict__ b2,
                       float* __restrict__ W23, float* __restrict__ bvA, float* __restrict__ bvB,
                       int* __restrict__ breal, int nbkt) {
  int t = threadIdx.x;
  for (int i = t; i < nbkt; i += TPB) breal[i] = 0;
  for (int idx = t; idx < 512; idx += TPB) {
    int i = idx >> 5, j = idx & 31;
    float s = 0.f;
    for (int k = 0; k < 24; k++) s += W2[i * 24 + k] * W3[k * 32 + j];
    W23[idx] = s;
  }
  __syncthreads();
  if (t < 32) {
    float sA = 0.f;
    for (int i = 0; i < 16; i++) sA += b1[i] * W23[i * 32 + t];
    bvA[t] = sA;
    float sB = 0.f;
    for (int k = 0; k < 24; k++) sB += b2[k] * W3[k * 32 + t];
    bvB[t] = sB;
  }
}

// ===================== hist2: LDS histogram + global accumulate =====================
__global__ void hist2_k(const int* __restrict__ col, int* __restrict__ breal,
                        int ne, int nbkt) {
  __shared__ int h[MAXBKT];
  int t = threadIdx.x;
  for (int i = t; i < nbkt; i += TPB) h[i] = 0;
  __syncthreads();
  int base = blockIdx.x * EPB;
#pragma unroll
  for (int k = 0; k < EPB / TPB; k++) {
    int idx = base + k * TPB + t;
    if (idx < ne) atomicAdd(&h[col[idx] >> 8], 1);
  }
  __syncthreads();
  for (int i = t; i < nbkt; i += TPB) if (h[i]) atomicAdd(&breal[i], h[i]);
}

// ===================== sbase: single block, dual scan (real + padded-capacity) ==========
__global__ void sbase_k(const int* __restrict__ breal, int* __restrict__ rbase,
                        int* __restrict__ base, int* __restrict__ cursor,
                        int nbkt, int nblk) {
  __shared__ int sr[TPB], sp[TPB];
  int t = threadIdx.x;
  int vr[2], vp[2]; int tr = 0, tp = 0;
#pragma unroll
  for (int k = 0; k < 2; k++) {
    int i = t * 2 + k; int R = 0, P = 0;
    if (i < nbkt) {
      R = breal[i];
      int mn = (nblk < R) ? nblk : R;
      P = (R + 3 * mn + 15) & ~15;
    }
    vr[k] = R; vp[k] = P; tr += R; tp += P;
  }
  sr[t] = tr; sp[t] = tp; __syncthreads();
  for (int off = 1; off < TPB; off <<= 1) {
    int ar = (t >= off) ? sr[t - off] : 0;
    int ap = (t >= off) ? sp[t - off] : 0;
    __syncthreads();
    sr[t] += ar; sp[t] += ap;
    __syncthreads();
  }
  int er = sr[t] - tr, ep = sp[t] - tp;
#pragma unroll
  for (int k = 0; k < 2; k++) {
    int i = t * 2 + k;
    if (i < nbkt) { rbase[i] = er; base[i] = ep; cursor[i] = ep; }
    er += vr[k]; ep += vp[k];
  }
}

// ===================== scatter: 512-thread, LDS count -> reserve -> stage -> copy ==========
__global__ void __launch_bounds__(STPB, 1)
scat_k(const int* __restrict__ row, const int* __restrict__ col,
       int* __restrict__ cursor, int* __restrict__ pairs,
       float* __restrict__ e0, float* __restrict__ e1,
       int ne, int nbkt) {
  __shared__ int sbase[MAXBKT], lofs[MAXBKT], lcur[MAXBKT], lsz[MAXBKT];
  __shared__ int ssc[STPB];
  __shared__ int stage[STAGE_CAP];
  int t = threadIdx.x;
  int b = blockIdx.x;
  for (int i = t; i < nbkt; i += STPB) lsz[i] = 0;
  __syncthreads();
  int base0 = b * EPB;
#pragma unroll
  for (int k = 0; k < EPB / STPB; k++) {
    int idx = base0 + k * STPB + t;
    if (idx < ne) atomicAdd(&lsz[col[idx] >> 8], 1);
  }
  __syncthreads();
  // 512-wide scan of round4 sizes (1 bucket/thread) + global reservation
  int L = (t < nbkt) ? lsz[t] : 0;
  int P = (L + 3) & ~3;
  ssc[t] = P; __syncthreads();
  for (int off = 1; off < STPB; off <<= 1) {
    int a = (t >= off) ? ssc[t - off] : 0;
    __syncthreads();
    ssc[t] += a;
    __syncthreads();
  }
  int excl = ssc[t] - P;
  if (t < nbkt) {
    lofs[t] = excl; lcur[t] = excl;
    if (L) sbase[t] = atomicAdd(&cursor[t], P);
  }
  __syncthreads();
  // scatter into stage + fused edge->float copy
#pragma unroll
  for (int k = 0; k < EPB / STPB; k++) {
    int idx = base0 + k * STPB + t;
    if (idx < ne) {
      int c = col[idx];
      int r = row[idx];
      int p = atomicAdd(&lcur[c >> 8], 1);
      stage[p] = (r << 8) | (c & 255);
      e0[idx] = (float)r;
      e1[idx] = (float)c;
    }
  }
  __syncthreads();
  // slack sentinels (<=3 per bucket)
  for (int i = t; i < nbkt; i += STPB) {
    int en = lofs[i] + lsz[i], pe = lofs[i] + ((lsz[i] + 3) & ~3);
    for (int p = en; p < pe; p++) stage[p] = SENT;
  }
  __syncthreads();
  int4* gp = (int4*)pairs;
  const int4* sp = (const int4*)stage;
  for (int i = t; i < nbkt; i += STPB) {
    int Li = lsz[i]; if (!Li) continue;
    int gb = sbase[i] >> 2, lb = lofs[i] >> 2, m = ((Li + 3) & ~3) >> 2;
    for (int q = 0; q < m; q++) gp[gb + q] = sp[lb + q];
  }
}

// ===================== pass 2: per-bucket CSR build =====================
__global__ void bbuild_k(const int* __restrict__ pairs, const int* __restrict__ base,
                         const int* __restrict__ cursor, const int* __restrict__ rbase,
                         int* __restrict__ rp, float* __restrict__ dinv,
                         int* __restrict__ csr, int n, int ne) {
  int bkt = blockIdx.x;
  int lo = bkt << 8;
  int t = threadIdx.x;
  int pstart = base[bkt];
  int pend   = cursor[bkt];
  int rbase_ = rbase[bkt];
  __shared__ int cnt[BNODES], sc[BNODES], pos[BNODES];
  cnt[t] = 0; __syncthreads();
  for (int p = pstart + t; p < pend; p += TPB) {
    int e = pairs[p];
    if (e >= 0) atomicAdd(&cnt[e & 255], 1);
  }
  __syncthreads();
  int own = cnt[t];
  sc[t] = own; __syncthreads();
  for (int off = 1; off < BNODES; off <<= 1) {
    int add = (t >= off) ? sc[t - off] : 0;
    __syncthreads();
    sc[t] += add;
    __syncthreads();
  }
  int excl = sc[t] - own;
  if (lo + t < n) {
    rp[lo + t] = rbase_ + excl;
    dinv[lo + t] = 1.0f / sqrtf((float)(own + 1));
  }
  pos[t] = rbase_ + excl;
  __syncthreads();
  for (int p = pstart + t; p < pend; p += TPB) {
    int e = pairs[p];
    if (e >= 0) {
      int q = atomicAdd(&pos[e & 255], 1);
      csr[q] = e >> 8;
    }
  }
  if (bkt == 0 && t == 0) rp[n] = ne;
}

// ===================== s0 = dinv * (x W1), fp16 output (16-wide) =====================
__global__ void gemm16h_k(const float* __restrict__ A, const float* __restrict__ A2, int nsplit,
                          const float* __restrict__ W, const float* __restrict__ dinv,
                          hf* __restrict__ out, int n) {
  constexpr int FIN = 32, FOUT = 16, FP = 16;
  constexpr int NODES = TPB / FP;
  __shared__ float Ws[FIN * FOUT];
  __shared__ float Hs[NODES * (FIN + 1)];
  int t = threadIdx.x;
  int base = blockIdx.x * NODES;
  for (int i = t; i < FIN * FOUT; i += TPB) Ws[i] = W[i];
  for (int i = t; i < NODES * FIN; i += TPB) {
    int nl = i / FIN, k = i - nl * FIN;
    int g = base + nl;
    float v = 0.f;
    if (g < n) v = (g < nsplit) ? A[(size_t)g * FIN + k] : A2[(size_t)(g - nsplit) * FIN + k];
    Hs[nl * (FIN + 1) + k] = v;
  }
  __syncthreads();
  int nl = t / FP, j = t % FP;
  int g = base + nl;
  if (g < n) {
    float acc = 0.f;
#pragma unroll
    for (int k = 0; k < FIN; k++) acc += Hs[nl * (FIN + 1) + k] * Ws[k * FOUT + j];
    out[(size_t)g * FOUT + j] = (hf)(acc * dinv[g]);
  }
}

// ===================== fp16 hop + fused scalar chain: 8 nodes/wave, aligned int4 csr ==========
__global__ void agghs_k(const h8* __restrict__ ts, const int* __restrict__ csr,
                        const int* __restrict__ rp, const float* __restrict__ dinv,
                        const float* __restrict__ sin_, float* __restrict__ u_out,
                        float* __restrict__ us_out, h8* __restrict__ outv, int n) {
  int wave = blockIdx.x * (TPB / 64) + (threadIdx.x >> 6);
  int lane = threadIdx.x & 63;
  int j = lane & 1;
  int grp = (lane >> 1) & 3;
  int nl = lane >> 3;
  int c = wave * 8 + nl;
  bool valid = (c < n);
  float acc[8] = {0.f, 0.f, 0.f, 0.f, 0.f, 0.f, 0.f, 0.f};
  float accS = 0.f;
  if (valid) {
    int s = rp[c], e = rp[c + 1];
    int ch0 = s >> 2, ch1 = (e + 3) >> 2;
    int nch = ch1 - ch0;
    int k0 = ch0 + ((nch * grp) >> 2);
    int k1 = ch0 + ((nch * (grp + 1)) >> 2);
    for (int ch = k0; ch < k1; ch++) {
      int base = ch << 2;
      int4 e4 = *(const int4*)(csr + base);   // 16B aligned always
      bool b0 = (base     >= s) & (base     < e);
      bool b1 = (base + 1 >= s) & (base + 1 < e);
      bool b2 = (base + 2 >= s) & (base + 2 < e);
      bool b3 = (base + 3 >= s) & (base + 3 < e);
      int r0 = b0 ? e4.x : 0;
      int r1 = b1 ? e4.y : 0;
      int r2 = b2 ? e4.z : 0;
      int r3 = b3 ? e4.w : 0;
      float m0 = b0 ? 1.f : 0.f, m1 = b1 ? 1.f : 0.f;
      float m2 = b2 ? 1.f : 0.f, m3 = b3 ? 1.f : 0.f;
      h8 v0 = ts[(r0 << 1) | j];
      h8 v1 = ts[(r1 << 1) | j];
      h8 v2 = ts[(r2 << 1) | j];
      h8 v3 = ts[(r3 << 1) | j];
      float sA = sin_[j ? r2 : r0];
      float sB = sin_[j ? r3 : r1];
      accS += sA * (j ? m2 : m0) + sB * (j ? m3 : m1);
#pragma unroll
      for (int k = 0; k < 8; k++)
        acc[k] += m0 * (float)v0[k] + m1 * (float)v1[k] + m2 * (float)v2[k] + m3 * (float)v3[k];
    }
  }
  accS += __shfl_xor(accS, 1, 64);
#pragma unroll
  for (int off = 2; off <= 4; off <<= 1) {
#pragma unroll
    for (int k = 0; k < 8; k++) acc[k] += __shfl_xor(acc[k], off, 64);
    accS += __shfl_xor(accS, off, 64);
  }
  if (valid && grp == 0) {
    h8 self = ts[(c << 1) | j];
    float d = dinv[c];
    float scl = d * d;
    h8 o;
#pragma unroll
    for (int k = 0; k < 8; k++) o[k] = (hf)(scl * (acc[k] + (float)self[k]));
    outv[(c << 1) | j] = o;
    if (j == 0) {
      float u = d * (accS + sin_[c]);
      u_out[c] = u;
      if (us_out) us_out[c] = u * d;
    }
  }
}

// ===================== final hop + combine + FUSED HEADS (32 nodes/block) =====================
__global__ void agghch_k(const h8* __restrict__ ts, const int* __restrict__ csr,
                         const int* __restrict__ rp, const float* __restrict__ dinv,
                         const float* __restrict__ a1, const float* __restrict__ a2,
                         const float* __restrict__ W23, const float* __restrict__ bvA,
                         const float* __restrict__ bvB, const float* __restrict__ b3,
                         const float* __restrict__ Ws1, const float* __restrict__ bs1,
                         const float* __restrict__ ws2, const float* __restrict__ bs2,
                         const float* __restrict__ We1, const float* __restrict__ be1,
                         const float* __restrict__ we2, const float* __restrict__ be2,
                         float* __restrict__ out, float* __restrict__ slog,
                         float* __restrict__ elog, float* __restrict__ pm, int n) {
  __shared__ float Ws[512], vA[32], vB[32], vb[32];
  __shared__ float t3s[32][17];
  __shared__ float h3s[32][33];
  __shared__ float W1s[512], W2s[768], b1s[16], b2s[24], v1s[16], v2s[24], sb2[2];
  __shared__ float sm1[32], su1[32], sm2[32], su2[32];
  int t = threadIdx.x;
  for (int i = t; i < 512; i += TPB) { Ws[i] = W23[i]; W1s[i] = Ws1[i]; }
  for (int i = t; i < 768; i += TPB) W2s[i] = We1[i];
  if (t < 32) { vA[t] = bvA[t]; vB[t] = bvB[t]; vb[t] = b3[t]; }
  if (t < 16) { b1s[t] = bs1[t]; v1s[t] = ws2[t]; }
  if (t < 24) { b2s[t] = be1[t]; v2s[t] = we2[t]; }
  if (t == 0) { sb2[0] = bs2[0]; sb2[1] = be2[0]; }
  int wave = t >> 6;
  int lane = t & 63;
  int j = lane & 1;
  int grp = (lane >> 1) & 3;
  int nl = lane >> 3;
  int nlb = wave * 8 + nl;              // node-in-block 0..31
  int c = blockIdx.x * 32 + nlb;
  bool valid = (c < n);
  float acc[8] = {0.f, 0.f, 0.f, 0.f, 0.f, 0.f, 0.f, 0.f};
  if (valid) {
    int s = rp[c], e = rp[c + 1];
    int ch0 = s >> 2, ch1 = (e + 3) >> 2;
    int nch = ch1 - ch0;
    int k0 = ch0 + ((nch * grp) >> 2);
    int k1 = ch0 + ((nch * (grp + 1)) >> 2);
    for (int ch = k0; ch < k1; ch++) {
      int base = ch << 2;
      int4 e4 = *(const int4*)(csr + base);
      bool b0 = (base     >= s) & (base     < e);
      bool b1 = (base + 1 >= s) & (base + 1 < e);
      bool b2 = (base + 2 >= s) & (base + 2 < e);
      bool b3b = (base + 3 >= s) & (base + 3 < e);
      int r0 = b0 ? e4.x : 0;
      int r1 = b1 ? e4.y : 0;
      int r2 = b2 ? e4.z : 0;
      int r3 = b3b ? e4.w : 0;
      float m0 = b0 ? 1.f : 0.f, m1 = b1 ? 1.f : 0.f;
      float m2 = b2 ? 1.f : 0.f, m3 = b3b ? 1.f : 0.f;
      h8 v0 = ts[(r0 << 1) | j];
      h8 v1 = ts[(r1 << 1) | j];
      h8 v2 = ts[(r2 << 1) | j];
      h8 v3 = ts[(r3 << 1) | j];
#pragma unroll
      for (int k = 0; k < 8; k++)
        acc[k] += m0 * (float)v0[k] + m1 * (float)v1[k] + m2 * (float)v2[k] + m3 * (float)v3[k];
    }
  }
#pragma unroll
  for (int off = 2; off <= 4; off <<= 1) {
#pragma unroll
    for (int k = 0; k < 8; k++) acc[k] += __shfl_xor(acc[k], off, 64);
  }
  if (valid && grp == 0) {
    h8 self = ts[(c << 1) | j];
    float d = dinv[c];
#pragma unroll
    for (int k = 0; k < 8; k++) t3s[nlb][j * 8 + k] = d * (acc[k] + (float)self[k]);
  }
  __syncthreads();
  // combine -> h3 (to global + LDS)
  int n2 = t >> 3, jb = t & 7;          // 32 nodes x 8 base channels
  int g = blockIdx.x * 32 + n2;
  if (g < n) {
    float av = a1[g], bv = a2[g];
#pragma unroll
    for (int q = 0; q < 4; q++) {
      int j2 = jb + q * 8;
      float acc2 = 0.f;
#pragma unroll
      for (int k = 0; k < 16; k++) acc2 += t3s[n2][k] * Ws[k * 32 + j2];
      float hv = acc2 + bv * vA[j2] + av * vB[j2] + vb[j2];
      out[(size_t)g * 32 + j2] = hv;
      h3s[n2][j2] = hv;
    }
  }
  __syncthreads();
  // heads: 8 threads per node, hidden units strided by 8
  float sP = 0.f, eP = 0.f;
  if (g < n) {
#pragma unroll
    for (int jj = 0; jj < 16; jj += 8) {
      int jh = jj + jb;
      float a = b1s[jh];
#pragma unroll
      for (int k = 0; k < 32; k++) a += h3s[n2][k] * W1s[k * 16 + jh];
      a = fminf(fmaxf(a, 0.f), 6.f);
      sP += a * v1s[jh];
    }
#pragma unroll
    for (int jj = 0; jj < 24; jj += 8) {
      int jh = jj + jb;
      float a = b2s[jh];
#pragma unroll
      for (int k = 0; k < 32; k++) a += h3s[n2][k] * W2s[k * 24 + jh];
      a = fminf(fmaxf(a, 0.f), 6.f);
      eP += a * v2s[jh];
    }
  }
#pragma unroll
  for (int off = 1; off <= 4; off <<= 1) {
    sP += __shfl_xor(sP, off, 64);
    eP += __shfl_xor(eP, off, 64);
  }
  if (jb == 0) {
    float s = -3.402823466e+38f, e2 = -3.402823466e+38f, w = 0.f;
    if (g < n) {
      s = sP + sb2[0]; e2 = eP + sb2[1]; w = 1.f;
      slog[g] = s; elog[g] = e2;
    }
    sm1[n2] = s;  su1[n2] = w;
    sm2[n2] = e2; su2[n2] = w;
  }
  __syncthreads();
  // block online-softmax partials over 32 nodes
  for (int st = 16; st > 0; st >>= 1) {
    if (t < st) {
      float M = fmaxf(sm1[t], sm1[t + st]);
      su1[t] = su1[t] * expf(sm1[t] - M) + su1[t + st] * expf(sm1[t + st] - M);
      sm1[t] = M;
      float M2 = fmaxf(sm2[t], sm2[t + st]);
      su2[t] = su2[t] * expf(sm2[t] - M2) + su2[t + st] * expf(sm2[t + st] - M2);
      sm2[t] = M2;
    }
    __syncthreads();
  }
  if (t == 0) {
    pm[blockIdx.x] = sm1[0]; pm[PMS + blockIdx.x] = su1[0];
    pm[2 * PMS + blockIdx.x] = sm2[0]; pm[3 * PMS + blockIdx.x] = su2[0];
  }
}

// ===================== fused probs write + gumbel argmax (finalizers folded in) ==========
template <int HEAD>
__global__ void pargmax_k(const float* __restrict__ logit, const float* __restrict__ pm, int nb,
                          const float* __restrict__ sval, const int* __restrict__ sidx,
                          float* __restrict__ outp, unsigned key, int n, int ngraph,
                          float* __restrict__ pval, int* __restrict__ pidx,
                          float* __restrict__ dnode) {
  int t = threadIdx.x;
  __shared__ float smM[TPB], smS[TPB];
  __shared__ float sv0[TPB]; __shared__ int si0[TPB];
  // inline softmax finalize over block partials
  const float* pmM = pm + (HEAD ? 2 * PMS : 0);
  const float* pmS = pm + (HEAD ? 3 * PMS : PMS);
  float m = -3.402823466e+38f, s0 = 0.f;
  for (int i = t; i < nb; i += TPB) {
    float bm = pmM[i], bs = pmS[i];
    float M = fmaxf(m, bm);
    s0 = s0 * expf(m - M) + bs * expf(bm - M); m = M;
  }
  smM[t] = m; smS[t] = s0; __syncthreads();
  for (int st = 128; st > 0; st >>= 1) {
    if (t < st) {
      float M = fmaxf(smM[t], smM[t + st]);
      smS[t] = smS[t] * expf(smM[t] - M) + smS[t + st] * expf(smM[t + st] - M);
      smM[t] = M;
    }
    __syncthreads();
  }
  float mx = smM[0], sm = smS[0];
  // inline start-argmax finalize (HEAD==1 only; sval/sidx have exactly 256 entries)
  int ban = -1;
  if (HEAD) {
    sv0[t] = sval[t]; si0[t] = sidx[t]; __syncthreads();
    for (int st = 128; st > 0; st >>= 1) {
      if (t < st) {
        float v2 = sv0[t + st]; int i2 = si0[t + st];
        if (v2 > sv0[t] || (v2 == sv0[t] && i2 < si0[t])) { sv0[t] = v2; si0[t] = i2; }
      }
      __syncthreads();
    }
    ban = si0[0];
    if (blockIdx.x == 0 && t == 0) dnode[0] = (float)ban;
  }
  float bv = -3.402823466e+38f;
  int bi = 0x7fffffff;
  for (int i = blockIdx.x * TPB + t; i < n; i += gridDim.x * TPB) {
    float p = expf(logit[i] - mx) / sm;
    if (HEAD == 0) { if (i >= ngraph) p = 0.f; }
    else           { if (i == ban) p = 0.f; }
    if (p == 0.f) p = 1e-10f;
    outp[i] = p;
    float v = logf(p) + jax_gumbel(key, (unsigned)i);
    if (v > bv) { bv = v; bi = i; }
  }
  __shared__ float sv[TPB]; __shared__ int si[TPB];
  sv[t] = bv; si[t] = bi; __syncthreads();
  for (int st = 128; st > 0; st >>= 1) {
    if (t < st) {
      float v2 = sv[t + st]; int i2 = si[t + st];
      if (v2 > sv[t] || (v2 == sv[t] && i2 < si[t])) { sv[t] = v2; si[t] = i2; }
    }
    __syncthreads();
  }
  if (t == 0) { pval[blockIdx.x] = sv[0]; pidx[blockIdx.x] = si[0]; }
}

__global__ void argmax_fin_end_k(const float* pval, const int* pidx, int nb,
                                 const float* dstart, float* p_end, float* p_e0, float* p_e1) {
  int t = threadIdx.x;
  float bv = (t < nb) ? pval[t] : -3.402823466e+38f;
  int bi = (t < nb) ? pidx[t] : 0x7fffffff;
  __shared__ float sv[TPB]; __shared__ int si[TPB];
  sv[t] = bv; si[t] = bi; __syncthreads();
  for (int st = 128; st > 0; st >>= 1) {
    if (t < st) {
      float v2 = sv[t + st]; int i2 = si[t + st];
      if (v2 > sv[t] || (v2 == sv[t] && i2 < si[t])) { sv[t] = v2; si[t] = i2; }
    }
    __syncthreads();
  }
  if (t == 0) {
    int en = si[0];
    p_end[0] = (float)en;
    p_e0[0] = dstart[0];
    p_e1[0] = (float)en;
  }
}

// ===================== launch =====================
extern "C" void kernel_launch(void* const* d_in, const int* in_sizes, int n_in,
                              void* d_out, int out_size, void* d_ws, size_t ws_size,
                              hipStream_t stream) {
  const float* x    = (const float*)d_in[0];
  const float* cand = (const float*)d_in[1];
  const int*   ei   = (const int*)d_in[2];
  const float* W1 = (const float*)d_in[3];  const float* b1  = (const float*)d_in[4];
  const float* W2 = (const float*)d_in[5];  const float* b2  = (const float*)d_in[6];
  const float* W3 = (const float*)d_in[7];  const float* b3  = (const float*)d_in[8];
  const float* Ws1= (const float*)d_in[9];  const float* bs1 = (const float*)d_in[10];
  const float* Ws2= (const float*)d_in[11]; const float* bs2 = (const float*)d_in[12];
  const float* We1= (const float*)d_in[13]; const float* be1 = (const float*)d_in[14];
  const float* We2= (const float*)d_in[15]; const float* be2 = (const float*)d_in[16];

  const int nG = in_sizes[0] / 32, nC = in_sizes[1] / 32;
  const int n  = nG + nC;            // 101000
  const int ne = in_sizes[2] / 2;    // 3200000

  float* out = (float*)d_out;
  const size_t OFF1 = (size_t)n * 32;
  const size_t OFF2 = OFF1 + n;
  const size_t OFF3 = OFF2 + n;
  const size_t OFF4 = OFF3 + 1;
  const size_t OFF5 = OFF4 + 1;     // edge_index_new region: 2*(ne+1) floats

  const int NBKT = (n + BNODES - 1) / BNODES;
  const int NBLK = (ne + EPB - 1) / EPB;

  // ---- workspace layout ----
  float* wf = (float*)d_ws;
  int*   wi = (int*)d_ws;
  size_t NP = (((size_t)n + 2) + 63) & ~(size_t)63;
  size_t o = 0;
  int*   rp    = wi + o; o += NP;
  int*   breal = wi + o; o += 512;
  int*   rbase = wi + o; o += 512;
  int*   bbase = wi + o; o += 512;
  int*   bcur  = wi + o; o += 512;
  float* dinv  = wf + o; o += NP;
  float* a1v   = wf + o; o += NP;
  float* a1s   = wf + o; o += NP;
  float* a2v   = wf + o; o += NP;
  float* w23   = wf + o; o += 512;
  float* bvA   = wf + o; o += 64;
  float* bvB   = wf + o; o += 64;
  float* slogv = wf + o; o += NP;
  float* elogv = wf + o; o += NP;
  float* pmA   = wf + o; o += 4 * PMS;
  float* aval  = wf + o; o += 512;
  int*   aidx  = wi + o; o += 512;
  hf*    hh0   = (hf*)(wf + o); o += (size_t)n * 8 + 64;    // n*16 halves (32B records)
  hf*    hh1   = (hf*)(wf + o); o += (size_t)n * 8 + 64;
  int*   csr   = wi + o; o += (size_t)ne + 64;
  int*   pairs = wi + o; o += (size_t)ne + 700000;          // ne + pad caps + slack

  const int* row = ei;
  const int* col = ei + ne;

  // ---- CSR build (R7 config; scat_k at 512 threads) ----
  prep_k<<<1, TPB, 0, stream>>>(W2, W3, b1, b2, w23, bvA, bvB, breal, NBKT);
  hist2_k<<<NBLK, TPB, 0, stream>>>(col, breal, ne, NBKT);
  sbase_k<<<1, TPB, 0, stream>>>(breal, rbase, bbase, bcur, NBKT, NBLK);
  scat_k<<<NBLK, STPB, 0, stream>>>(row, col, bcur, pairs,
                                    out + OFF5, out + OFF5 + ne + 1, ne, NBKT);
  bbuild_k<<<NBKT, TPB, 0, stream>>>(pairs, bbase, bcur, rbase, rp, dinv, csr, n, ne);

  // ---- fused-linear GCN: h3 = A^3 (x W1) W23 + a2*bvA + a1*bvB + b3 ----
  gemm16h_k<<<(n + 15) / 16, TPB, 0, stream>>>(x, cand, nG, W1, dinv, hh0, n);
  int gH = (n + 31) / 32;
  agghs_k<<<gH, TPB, 0, stream>>>((const h8*)hh0, csr, rp, dinv, dinv, a1v, a1s, (h8*)hh1, n);
  agghs_k<<<gH, TPB, 0, stream>>>((const h8*)hh1, csr, rp, dinv, a1s, a2v, nullptr, (h8*)hh0, n);
  agghch_k<<<gH, TPB, 0, stream>>>((const h8*)hh0, csr, rp, dinv, a1v, a2v,
                                   w23, bvA, bvB, b3,
                                   Ws1, bs1, Ws2, bs2, We1, be1, We2, be2,
                                   out, slogv, elogv, pmA, n);

  // start head: probs + categorical(42); softmax finalize inlined per block
  pargmax_k<0><<<256, TPB, 0, stream>>>(slogv, pmA, gH, nullptr, nullptr,
                                        out + OFF1, 42u, n, nG, aval, aidx, nullptr);

  // end head: probs (zero at start) + categorical(43); ban derived per block
  pargmax_k<1><<<256, TPB, 0, stream>>>(elogv, pmA, gH, aval, aidx,
                                        out + OFF2, 43u, n, nG, aval + 256, aidx + 256,
                                        out + OFF3);
  argmax_fin_end_k<<<1, TPB, 0, stream>>>(aval + 256, aidx + 256, 256, out + OFF3,
                                          out + OFF4, out + OFF5 + ne, out + OFF5 + 2 * (size_t)ne + 1);
}